// Round 12
// baseline (455.713 us; speedup 1.0000x reference)
//
#include <hip/hip_runtime.h>

#define D_IN 150528
#define FEAT 256
#define HID 64
#define T 4
#define B 8
#define NROWS 1280            // 5 * 256 rows (W1 + 4x dW1)
#define D4 37632              // D_IN / 4 float4 per row
#define KS 28                 // K splits
#define JSTEPS 21             // 588 / 28 (64-float4 steps per chunk)
#define RPW 4                 // rows per wave
#define RPB 16                // rows per block (4 waves)
#define NRB 80                // 1280 / 16

typedef float f4 __attribute__((ext_vector_type(4)));

// ---------------- stage 1: the 5 batched GEMVs over K=150528 ----------------
// RPW=4 (x-redundancy 1.5GB, the r11 lesson) + GENUINE 64-VGPR fit (the r7
// lesson: 64-reg occupancy wins; r7 spilled 400MB to get it). Register diet:
// per-b xv consumption (live ~3, not 32), row pointers scalarized via
// readfirstlane (SGPR saddr), nontemporal matrix loads so the 771MB stream
// doesn't evict x from L2. (256,8): 8 waves/SIMD, grid (28,80)=2240 ~ 8.75/CU.
__global__ __launch_bounds__(256, 8) void stage1(
    const float* __restrict__ x, const float* __restrict__ W1,
    const float* __restrict__ dW1, float* __restrict__ partial) {
  const int ks   = blockIdx.x;                        // 0..27
  const int rb   = blockIdx.y;                        // 0..79
  const int wid  = threadIdx.x >> 6;                  // wave 0..3
  const int lane = threadIdx.x & 63;
  // wave-uniform row base -> SGPR
  const int r0   = __builtin_amdgcn_readfirstlane(rb * RPB + wid * RPW);
  const int kb4  = ks * (JSTEPS * 64);                // float4 offset in K

  const f4* rp[RPW];                                  // wave-uniform -> SGPRs
#pragma unroll
  for (int i = 0; i < RPW; ++i) {
    int r = r0 + i, m = r >> 8, f = r & 255;
    const float* base = (m == 0) ? (W1 + (size_t)f * D_IN)
                                 : (dW1 + ((size_t)(m - 1) * FEAT + f) * D_IN);
    rp[i] = (const f4*)base + kb4;
  }
  const f4* x4 = (const f4*)x + kb4;                  // + b*D4 + idx

  float acc[RPW][B];
#pragma unroll
  for (int i = 0; i < RPW; ++i)
#pragma unroll
    for (int b = 0; b < B; ++b) acc[i][b] = 0.f;

  for (int j = 0; j < JSTEPS; ++j) {
    const int idx = j * 64 + lane;
    f4 mv[RPW];
#pragma unroll
    for (int i = 0; i < RPW; ++i)
      mv[i] = __builtin_nontemporal_load(&rp[i][idx]); // 4x 1KB HBM streams
#pragma unroll
    for (int b = 0; b < B; ++b) {                     // one xv live at a time
      f4 xv = x4[(size_t)b * D4 + idx];               // L2-resident (nt above)
#pragma unroll
      for (int i = 0; i < RPW; ++i)
        acc[i][b] += mv[i][0] * xv[0] + mv[i][1] * xv[1] +
                     mv[i][2] * xv[2] + mv[i][3] * xv[3];
    }
  }

  // full-wave butterfly per (i,b); lanes 0..31 keep (row i=lane>>3, b=lane&7)
  float outv = 0.f;
#pragma unroll
  for (int i = 0; i < RPW; ++i)
#pragma unroll
    for (int b = 0; b < B; ++b) {
      float v = acc[i][b];
      v += __shfl_xor(v, 1);
      v += __shfl_xor(v, 2);
      v += __shfl_xor(v, 4);
      v += __shfl_xor(v, 8);
      v += __shfl_xor(v, 16);
      v += __shfl_xor(v, 32);
      if (lane == i * B + b) outv = v;                // compile-time acc index
    }
  if (lane < RPW * B)                                 // 32 consecutive floats
    partial[((size_t)ks * NROWS + r0) * B + lane] = outv;
}

// ---------------- stage 2: reduce K-splits, add biases ----------------
__global__ __launch_bounds__(256) void stage2(
    const float* __restrict__ partial, const float* __restrict__ b1,
    const float* __restrict__ db1, float* __restrict__ hp) {
  int idx = blockIdx.x * 256 + threadIdx.x;           // 0..10239
  int r = idx >> 3, b = idx & 7;
  int m = r >> 8, f = r & 255;
  float s = (m == 0) ? b1[f] : db1[(m - 1) * FEAT + f];
  for (int ks = 0; ks < KS; ++ks)
    s += partial[((size_t)ks * NROWS + r) * B + b];
  hp[idx] = s;                                        // hp[r][b]
}

// ---------------- stage 3: everything after hpre, one block per batch ------
__global__ __launch_bounds__(256) void stage3(
    const float* __restrict__ hp, const float* __restrict__ W2,
    const float* __restrict__ b2, const float* __restrict__ mW1,
    const float* __restrict__ mb1, const float* __restrict__ mW2,
    const float* __restrict__ mb2, const float* __restrict__ dW2,
    const float* __restrict__ db2, float* __restrict__ out) {
  __shared__ float h_l[FEAT];
  __shared__ float base_l[FEAT];
  __shared__ float u_l[FEAT];
  __shared__ float mid_l[HID];
  __shared__ float c_l[T];
  const int b = blockIdx.x;                           // batch
  const int g = threadIdx.x;                          // feature

  const float hpre = hp[(size_t)g * B + b];
  h_l[g] = hpre > 0.f ? hpre : 0.f;
  __syncthreads();

  // base[g] = b2[g] + h·W2[g]
  const float4* h4 = (const float4*)h_l;
  const float4* w4 = (const float4*)(W2 + (size_t)g * FEAT);
  {
    float s = b2[g];
    for (int f4i = 0; f4i < FEAT / 4; ++f4i) {
      float4 hh = h4[f4i], w = w4[f4i];
      s += hh.x * w.x + hh.y * w.y + hh.z * w.z + hh.w * w.w;
    }
    base_l[g] = s;
  }
  __syncthreads();

  // mid[hid] = relu(mb1 + base·mW1[hid])   (threads 0..63)
  if (g < HID) {
    float s = mb1[g];
    const float4* b4 = (const float4*)base_l;
    const float4* mw = (const float4*)(mW1 + (size_t)g * FEAT);
    for (int f4i = 0; f4i < FEAT / 4; ++f4i) {
      float4 bb = b4[f4i], w = mw[f4i];
      s += bb.x * w.x + bb.y * w.y + bb.z * w.z + bb.w * w.w;
    }
    mid_l[g] = s > 0.f ? s : 0.f;
  }
  __syncthreads();

  // coefs[t]   (threads 0..3)
  if (g < T) {
    float s = mb2[g];
    const float* wrow = mW2 + g * HID;
    for (int hh = 0; hh < HID; ++hh) s += mid_l[hh] * wrow[hh];
    c_l[g] = s;
  }
  __syncthreads();

  // u[g] = (hpre>0) * sum_t c[t]*dhpre[t][g]
  {
    float s = 0.f;
    if (hpre > 0.f) {
#pragma unroll
      for (int t = 0; t < T; ++t)
        s += c_l[t] * hp[((size_t)(1 + t) * FEAT + g) * B + b];
    }
    u_l[g] = s;
  }
  __syncthreads();

  // out[b][g] = base + sum_t c*db2 + u·W2[g] + sum_t c_t*(h·dW2[t][g])
  float o = base_l[g];
#pragma unroll
  for (int t = 0; t < T; ++t) o += c_l[t] * db2[t * FEAT + g];
  const float4* u4 = (const float4*)u_l;
  float a1 = 0.f;
  float a2[T] = {0.f, 0.f, 0.f, 0.f};
  for (int f4i = 0; f4i < FEAT / 4; ++f4i) {
    float4 w = w4[f4i], uu = u4[f4i], hh = h4[f4i];
    a1 += uu.x * w.x + uu.y * w.y + uu.z * w.z + uu.w * w.w;
#pragma unroll
    for (int t = 0; t < T; ++t) {
      float4 dv = ((const float4*)(dW2 + (((size_t)t * FEAT) + g) * FEAT))[f4i];
      a2[t] += hh.x * dv.x + hh.y * dv.y + hh.z * dv.z + hh.w * dv.w;
    }
  }
  o += a1;
#pragma unroll
  for (int t = 0; t < T; ++t) o += c_l[t] * a2[t];
  out[b * FEAT + g] = o;
}

extern "C" void kernel_launch(void* const* d_in, const int* in_sizes, int n_in,
                              void* d_out, int out_size, void* d_ws, size_t ws_size,
                              hipStream_t stream) {
  const float* x   = (const float*)d_in[0];
  const float* W1  = (const float*)d_in[1];
  const float* b1  = (const float*)d_in[2];
  const float* W2  = (const float*)d_in[3];
  const float* b2  = (const float*)d_in[4];
  const float* mW1 = (const float*)d_in[5];
  const float* mb1 = (const float*)d_in[6];
  const float* mW2 = (const float*)d_in[7];
  const float* mb2 = (const float*)d_in[8];
  const float* dW1 = (const float*)d_in[9];
  const float* db1 = (const float*)d_in[10];
  const float* dW2 = (const float*)d_in[11];
  const float* db2 = (const float*)d_in[12];
  float* out = (float*)d_out;

  float* ws = (float*)d_ws;
  float* P  = ws;                              // [28][1280][8] = 286720
  float* HP = P + (size_t)KS * NROWS * B;      // [1280][8] = 10240

  stage1<<<dim3(KS, NRB), 256, 0, stream>>>(x, W1, dW1, P);
  stage2<<<40, 256, 0, stream>>>(P, b1, db1, HP);
  stage3<<<B, 256, 0, stream>>>(HP, W2, b2, mW1, mb1, mW2, mb2, dW2, db2, out);
}

// Round 14
// 229.269 us; speedup vs baseline: 1.9877x; 1.9877x over previous
//
#include <hip/hip_runtime.h>

#define D_IN 150528
#define FEAT 256
#define HID 64
#define T 4
#define B 8
#define NROWS 1280            // 5 * 256 rows (W1 + 4x dW1)
#define D4 37632              // D_IN / 4 float4 per row
#define KS 21                 // K splits
#define JSTEPS 28             // 588 / 21 (64-float4 steps per chunk)
#define RPW 4                 // rows per wave
#define RPB 16                // rows per block (4 waves)
#define NRB 80                // 1280 / 16

typedef float f4 __attribute__((ext_vector_type(4)));

// ---------------- stage 1: the 5 batched GEMVs over K=150528 ----------------
// Calibration (r8/r9/r12): launch_bounds(256,N) caps VGPR at 256/N -> (256,4)
// gives a 64-reg budget. This structure GENUINELY needs ~58 (acc 32 + mv 16 +
// xv ~4 + addr ~6; per-b xv consumption, SGPR row ptrs via readfirstlane) so
// it fits 64 with ZERO spill -- r7's winning register class without r7's
// 400MB scratch traffic. 64-reg clean => HW runs 8 waves/SIMD (m69 steps).
// Grid (21,80)=1680 blocks ~ 6.6/CU < 8/CU capacity: fully resident, no tail.
__global__ __launch_bounds__(256, 4) void stage1(
    const float* __restrict__ x, const float* __restrict__ W1,
    const float* __restrict__ dW1, float* __restrict__ partial) {
  const int ks   = blockIdx.x;                        // 0..20
  const int rb   = blockIdx.y;                        // 0..79
  const int wid  = threadIdx.x >> 6;                  // wave 0..3
  const int lane = threadIdx.x & 63;
  // wave-uniform row base -> SGPR
  const int r0   = __builtin_amdgcn_readfirstlane(rb * RPB + wid * RPW);
  const int kb4  = ks * (JSTEPS * 64);                // float4 offset in K

  const f4* rp[RPW];                                  // wave-uniform -> SGPRs
#pragma unroll
  for (int i = 0; i < RPW; ++i) {
    int r = r0 + i, m = r >> 8, f = r & 255;
    const float* base = (m == 0) ? (W1 + (size_t)f * D_IN)
                                 : (dW1 + ((size_t)(m - 1) * FEAT + f) * D_IN);
    rp[i] = (const f4*)base + kb4;
  }
  const f4* x4 = (const f4*)x + kb4;                  // + b*D4 + idx

  float acc[RPW][B];
#pragma unroll
  for (int i = 0; i < RPW; ++i)
#pragma unroll
    for (int b = 0; b < B; ++b) acc[i][b] = 0.f;

  for (int j = 0; j < JSTEPS; ++j) {
    const int idx = j * 64 + lane;
    f4 mv[RPW];
#pragma unroll
    for (int i = 0; i < RPW; ++i)
      mv[i] = __builtin_nontemporal_load(&rp[i][idx]); // 4x 1KB HBM streams
#pragma unroll
    for (int b = 0; b < B; ++b) {                     // one xv live at a time
      f4 xv = x4[(size_t)b * D4 + idx];               // L2-resident
#pragma unroll
      for (int i = 0; i < RPW; ++i)
        acc[i][b] += mv[i][0] * xv[0] + mv[i][1] * xv[1] +
                     mv[i][2] * xv[2] + mv[i][3] * xv[3];
    }
  }

  // full-wave butterfly per (i,b); lanes 0..31 keep (row i=lane>>3, b=lane&7)
  float outv = 0.f;
#pragma unroll
  for (int i = 0; i < RPW; ++i)
#pragma unroll
    for (int b = 0; b < B; ++b) {
      float v = acc[i][b];
      v += __shfl_xor(v, 1);
      v += __shfl_xor(v, 2);
      v += __shfl_xor(v, 4);
      v += __shfl_xor(v, 8);
      v += __shfl_xor(v, 16);
      v += __shfl_xor(v, 32);
      if (lane == i * B + b) outv = v;                // compile-time acc index
    }
  if (lane < RPW * B)                                 // 32 consecutive floats
    partial[((size_t)ks * NROWS + r0) * B + lane] = outv;
}

// ---------------- stage 2: reduce K-splits, add biases ----------------
__global__ __launch_bounds__(256) void stage2(
    const float* __restrict__ partial, const float* __restrict__ b1,
    const float* __restrict__ db1, float* __restrict__ hp) {
  int idx = blockIdx.x * 256 + threadIdx.x;           // 0..10239
  int r = idx >> 3, b = idx & 7;
  int m = r >> 8, f = r & 255;
  float s = (m == 0) ? b1[f] : db1[(m - 1) * FEAT + f];
  for (int ks = 0; ks < KS; ++ks)
    s += partial[((size_t)ks * NROWS + r) * B + b];
  hp[idx] = s;                                        // hp[r][b]
}

// ---------------- stage 3: everything after hpre, one block per batch ------
__global__ __launch_bounds__(256) void stage3(
    const float* __restrict__ hp, const float* __restrict__ W2,
    const float* __restrict__ b2, const float* __restrict__ mW1,
    const float* __restrict__ mb1, const float* __restrict__ mW2,
    const float* __restrict__ mb2, const float* __restrict__ dW2,
    const float* __restrict__ db2, float* __restrict__ out) {
  __shared__ float h_l[FEAT];
  __shared__ float base_l[FEAT];
  __shared__ float u_l[FEAT];
  __shared__ float mid_l[HID];
  __shared__ float c_l[T];
  const int b = blockIdx.x;                           // batch
  const int g = threadIdx.x;                          // feature

  const float hpre = hp[(size_t)g * B + b];
  h_l[g] = hpre > 0.f ? hpre : 0.f;
  __syncthreads();

  // base[g] = b2[g] + h·W2[g]
  const float4* h4 = (const float4*)h_l;
  const float4* w4 = (const float4*)(W2 + (size_t)g * FEAT);
  {
    float s = b2[g];
    for (int f4i = 0; f4i < FEAT / 4; ++f4i) {
      float4 hh = h4[f4i], w = w4[f4i];
      s += hh.x * w.x + hh.y * w.y + hh.z * w.z + hh.w * w.w;
    }
    base_l[g] = s;
  }
  __syncthreads();

  // mid[hid] = relu(mb1 + base·mW1[hid])   (threads 0..63)
  if (g < HID) {
    float s = mb1[g];
    const float4* b4 = (const float4*)base_l;
    const float4* mw = (const float4*)(mW1 + (size_t)g * FEAT);
    for (int f4i = 0; f4i < FEAT / 4; ++f4i) {
      float4 bb = b4[f4i], w = mw[f4i];
      s += bb.x * w.x + bb.y * w.y + bb.z * w.z + bb.w * w.w;
    }
    mid_l[g] = s > 0.f ? s : 0.f;
  }
  __syncthreads();

  // coefs[t]   (threads 0..3)
  if (g < T) {
    float s = mb2[g];
    const float* wrow = mW2 + g * HID;
    for (int hh = 0; hh < HID; ++hh) s += mid_l[hh] * wrow[hh];
    c_l[g] = s;
  }
  __syncthreads();

  // u[g] = (hpre>0) * sum_t c[t]*dhpre[t][g]
  {
    float s = 0.f;
    if (hpre > 0.f) {
#pragma unroll
      for (int t = 0; t < T; ++t)
        s += c_l[t] * hp[((size_t)(1 + t) * FEAT + g) * B + b];
    }
    u_l[g] = s;
  }
  __syncthreads();

  // out[b][g] = base + sum_t c*db2 + u·W2[g] + sum_t c_t*(h·dW2[t][g])
  float o = base_l[g];
#pragma unroll
  for (int t = 0; t < T; ++t) o += c_l[t] * db2[t * FEAT + g];
  const float4* u4 = (const float4*)u_l;
  float a1 = 0.f;
  float a2[T] = {0.f, 0.f, 0.f, 0.f};
  for (int f4i = 0; f4i < FEAT / 4; ++f4i) {
    float4 w = w4[f4i], uu = u4[f4i], hh = h4[f4i];
    a1 += uu.x * w.x + uu.y * w.y + uu.z * w.z + uu.w * w.w;
#pragma unroll
    for (int t = 0; t < T; ++t) {
      float4 dv = ((const float4*)(dW2 + (((size_t)t * FEAT) + g) * FEAT))[f4i];
      a2[t] += hh.x * dv.x + hh.y * dv.y + hh.z * dv.z + hh.w * dv.w;
    }
  }
  o += a1;
#pragma unroll
  for (int t = 0; t < T; ++t) o += c_l[t] * a2[t];
  out[b * FEAT + g] = o;
}

extern "C" void kernel_launch(void* const* d_in, const int* in_sizes, int n_in,
                              void* d_out, int out_size, void* d_ws, size_t ws_size,
                              hipStream_t stream) {
  const float* x   = (const float*)d_in[0];
  const float* W1  = (const float*)d_in[1];
  const float* b1  = (const float*)d_in[2];
  const float* W2  = (const float*)d_in[3];
  const float* b2  = (const float*)d_in[4];
  const float* mW1 = (const float*)d_in[5];
  const float* mb1 = (const float*)d_in[6];
  const float* mW2 = (const float*)d_in[7];
  const float* mb2 = (const float*)d_in[8];
  const float* dW1 = (const float*)d_in[9];
  const float* db1 = (const float*)d_in[10];
  const float* dW2 = (const float*)d_in[11];
  const float* db2 = (const float*)d_in[12];
  float* out = (float*)d_out;

  float* ws = (float*)d_ws;
  float* P  = ws;                              // [21][1280][8] = 215040
  float* HP = P + (size_t)KS * NROWS * B;      // [1280][8] = 10240

  stage1<<<dim3(KS, NRB), 256, 0, stream>>>(x, W1, dW1, P);
  stage2<<<40, 256, 0, stream>>>(P, b1, db1, HP);
  stage3<<<B, 256, 0, stream>>>(HP, W2, b2, mW1, mb1, mW2, mb2, dW2, db2, out);
}

// Round 17
// 218.961 us; speedup vs baseline: 2.0813x; 1.0471x over previous
//
#include <hip/hip_runtime.h>

#define D_IN 150528
#define FEAT 256
#define HID 64
#define T 4
#define B 8
#define NROWS 1280            // 5 * 256 rows (W1 + 4x dW1)
#define D4 37632              // D_IN / 4 float4 per row
#define KS 21                 // K splits
#define JSTEPS 28             // 588 / 21 (64-float4 steps per chunk)
#define RPW 4                 // rows per wave
#define RPB 16                // rows per block (4 waves)
#define NRB 80                // 1280 / 16
#define NBLK (KS * NRB)       // 1680 = 8 * 210

typedef float f4 __attribute__((ext_vector_type(4)));

// ---------------- stage 1: the 5 batched GEMVs over K=150528 ----------------
// r14 structure (64-reg clean, 229us) + XCD-aware block swizzle. Diagnosis:
// x traffic (B/RPW = 2x matrix = 1.4GB) is served by L3 because default
// round-robin dispatch gives every XCD blocks of ALL 21 ks-chunks -> x
// working set 4.8MB > 4MB L2/XCD, evicted by the matrix stream. Swizzle
// vid=(bid&7)*210+(bid>>3) gives each XCD a 2-3 ks band -> x window ~670KB
// stays L2-resident; L3 carries only the 700MB matrix stream.
__global__ __launch_bounds__(256, 4) void stage1(
    const float* __restrict__ x, const float* __restrict__ W1,
    const float* __restrict__ dW1, float* __restrict__ partial) {
  const int bid  = blockIdx.x;                        // 0..1679
  const int vid  = (bid & 7) * (NBLK / 8) + (bid >> 3); // bijective, 1680%8==0
  const int ks   = vid / NRB;                         // 0..20 (XCD-banded)
  const int rb   = vid % NRB;                         // 0..79
  const int wid  = threadIdx.x >> 6;                  // wave 0..3
  const int lane = threadIdx.x & 63;
  // wave-uniform row base -> SGPR
  const int r0   = __builtin_amdgcn_readfirstlane(rb * RPB + wid * RPW);
  const int kb4  = ks * (JSTEPS * 64);                // float4 offset in K

  const f4* rp[RPW];                                  // wave-uniform -> SGPRs
#pragma unroll
  for (int i = 0; i < RPW; ++i) {
    int r = r0 + i, m = r >> 8, f = r & 255;
    const float* base = (m == 0) ? (W1 + (size_t)f * D_IN)
                                 : (dW1 + ((size_t)(m - 1) * FEAT + f) * D_IN);
    rp[i] = (const f4*)base + kb4;
  }
  const f4* x4 = (const f4*)x + kb4;                  // + b*D4 + idx

  float acc[RPW][B];
#pragma unroll
  for (int i = 0; i < RPW; ++i)
#pragma unroll
    for (int b = 0; b < B; ++b) acc[i][b] = 0.f;

  for (int j = 0; j < JSTEPS; ++j) {
    const int idx = j * 64 + lane;
    f4 mv[RPW];
#pragma unroll
    for (int i = 0; i < RPW; ++i)
      mv[i] = __builtin_nontemporal_load(&rp[i][idx]); // 4x 1KB HBM streams
#pragma unroll
    for (int b = 0; b < B; ++b) {                     // one xv live at a time
      f4 xv = x4[(size_t)b * D4 + idx];               // L2-resident now
#pragma unroll
      for (int i = 0; i < RPW; ++i)
        acc[i][b] += mv[i][0] * xv[0] + mv[i][1] * xv[1] +
                     mv[i][2] * xv[2] + mv[i][3] * xv[3];
    }
  }

  // full-wave butterfly per (i,b); lanes 0..31 keep (row i=lane>>3, b=lane&7)
  float outv = 0.f;
#pragma unroll
  for (int i = 0; i < RPW; ++i)
#pragma unroll
    for (int b = 0; b < B; ++b) {
      float v = acc[i][b];
      v += __shfl_xor(v, 1);
      v += __shfl_xor(v, 2);
      v += __shfl_xor(v, 4);
      v += __shfl_xor(v, 8);
      v += __shfl_xor(v, 16);
      v += __shfl_xor(v, 32);
      if (lane == i * B + b) outv = v;                // compile-time acc index
    }
  if (lane < RPW * B)                                 // 32 consecutive floats
    partial[((size_t)ks * NROWS + r0) * B + lane] = outv;
}

// ---------------- stage 2: reduce K-splits, add biases ----------------
__global__ __launch_bounds__(256) void stage2(
    const float* __restrict__ partial, const float* __restrict__ b1,
    const float* __restrict__ db1, float* __restrict__ hp) {
  int idx = blockIdx.x * 256 + threadIdx.x;           // 0..10239
  int r = idx >> 3, b = idx & 7;
  int m = r >> 8, f = r & 255;
  float s = (m == 0) ? b1[f] : db1[(m - 1) * FEAT + f];
  for (int ks = 0; ks < KS; ++ks)
    s += partial[((size_t)ks * NROWS + r) * B + b];
  hp[idx] = s;                                        // hp[r][b]
}

// ---------------- stage 3: everything after hpre, one block per batch ------
__global__ __launch_bounds__(256) void stage3(
    const float* __restrict__ hp, const float* __restrict__ W2,
    const float* __restrict__ b2, const float* __restrict__ mW1,
    const float* __restrict__ mb1, const float* __restrict__ mW2,
    const float* __restrict__ mb2, const float* __restrict__ dW2,
    const float* __restrict__ db2, float* __restrict__ out) {
  __shared__ float h_l[FEAT];
  __shared__ float base_l[FEAT];
  __shared__ float u_l[FEAT];
  __shared__ float mid_l[HID];
  __shared__ float c_l[T];
  const int b = blockIdx.x;                           // batch
  const int g = threadIdx.x;                          // feature

  const float hpre = hp[(size_t)g * B + b];
  h_l[g] = hpre > 0.f ? hpre : 0.f;
  __syncthreads();

  // base[g] = b2[g] + h·W2[g]
  const float4* h4 = (const float4*)h_l;
  const float4* w4 = (const float4*)(W2 + (size_t)g * FEAT);
  {
    float s = b2[g];
    for (int f4i = 0; f4i < FEAT / 4; ++f4i) {
      float4 hh = h4[f4i], w = w4[f4i];
      s += hh.x * w.x + hh.y * w.y + hh.z * w.z + hh.w * w.w;
    }
    base_l[g] = s;
  }
  __syncthreads();

  // mid[hid] = relu(mb1 + base·mW1[hid])   (threads 0..63)
  if (g < HID) {
    float s = mb1[g];
    const float4* b4 = (const float4*)base_l;
    const float4* mw = (const float4*)(mW1 + (size_t)g * FEAT);
    for (int f4i = 0; f4i < FEAT / 4; ++f4i) {
      float4 bb = b4[f4i], w = mw[f4i];
      s += bb.x * w.x + bb.y * w.y + bb.z * w.z + bb.w * w.w;
    }
    mid_l[g] = s > 0.f ? s : 0.f;
  }
  __syncthreads();

  // coefs[t]   (threads 0..3)
  if (g < T) {
    float s = mb2[g];
    const float* wrow = mW2 + g * HID;
    for (int hh = 0; hh < HID; ++hh) s += mid_l[hh] * wrow[hh];
    c_l[g] = s;
  }
  __syncthreads();

  // u[g] = (hpre>0) * sum_t c[t]*dhpre[t][g]
  {
    float s = 0.f;
    if (hpre > 0.f) {
#pragma unroll
      for (int t = 0; t < T; ++t)
        s += c_l[t] * hp[((size_t)(1 + t) * FEAT + g) * B + b];
    }
    u_l[g] = s;
  }
  __syncthreads();

  // out[b][g] = base + sum_t c*db2 + u·W2[g] + sum_t c_t*(h·dW2[t][g])
  float o = base_l[g];
#pragma unroll
  for (int t = 0; t < T; ++t) o += c_l[t] * db2[t * FEAT + g];
  const float4* u4 = (const float4*)u_l;
  float a1 = 0.f;
  float a2[T] = {0.f, 0.f, 0.f, 0.f};
  for (int f4i = 0; f4i < FEAT / 4; ++f4i) {
    float4 w = w4[f4i], uu = u4[f4i], hh = h4[f4i];
    a1 += uu.x * w.x + uu.y * w.y + uu.z * w.z + uu.w * w.w;
#pragma unroll
    for (int t = 0; t < T; ++t) {
      float4 dv = ((const float4*)(dW2 + (((size_t)t * FEAT) + g) * FEAT))[f4i];
      a2[t] += hh.x * dv.x + hh.y * dv.y + hh.z * dv.z + hh.w * dv.w;
    }
  }
  o += a1;
#pragma unroll
  for (int t = 0; t < T; ++t) o += c_l[t] * a2[t];
  out[b * FEAT + g] = o;
}

extern "C" void kernel_launch(void* const* d_in, const int* in_sizes, int n_in,
                              void* d_out, int out_size, void* d_ws, size_t ws_size,
                              hipStream_t stream) {
  const float* x   = (const float*)d_in[0];
  const float* W1  = (const float*)d_in[1];
  const float* b1  = (const float*)d_in[2];
  const float* W2  = (const float*)d_in[3];
  const float* b2  = (const float*)d_in[4];
  const float* mW1 = (const float*)d_in[5];
  const float* mb1 = (const float*)d_in[6];
  const float* mW2 = (const float*)d_in[7];
  const float* mb2 = (const float*)d_in[8];
  const float* dW1 = (const float*)d_in[9];
  const float* db1 = (const float*)d_in[10];
  const float* dW2 = (const float*)d_in[11];
  const float* db2 = (const float*)d_in[12];
  float* out = (float*)d_out;

  float* ws = (float*)d_ws;
  float* P  = ws;                              // [21][1280][8] = 215040
  float* HP = P + (size_t)KS * NROWS * B;      // [1280][8] = 10240

  stage1<<<NBLK, 256, 0, stream>>>(x, W1, dW1, P);
  stage2<<<40, 256, 0, stream>>>(P, b1, db1, HP);
  stage3<<<B, 256, 0, stream>>>(HP, W2, b2, mW1, mb1, mW2, mb2, dW2, db2, out);
}